// Round 11
// baseline (64.179 us; speedup 1.0000x reference)
//
#include <hip/hip_runtime.h>
#include <math.h>

// Problem dims (fixed by setup_inputs)
#define B_ 4
#define G_ 8
#define D_ 8
#define H_ 256
#define W_ 320
#define N_ 9
constexpr int HW  = H_ * W_;
constexpr int DHW = D_ * HW;
constexpr int BHW = B_ * HW;
constexpr float BN_EPS = 1e-5f;

// fp16 quad: {xn(2j), s(2j), xn(2j+1), s(2j+1)} for one pixel, one depth-pair.
typedef _Float16 h4v __attribute__((ext_vector_type(4)));
// two adjacent pixels' quads (16 B)
typedef _Float16 h8v __attribute__((ext_vector_type(8)));

// d_ws float layout:
//   [0..127]    fw0[16][8]   (BN-folded layer0 weights)
//   [128..143]  fb0[16]      (BN-folded layer0 bias)
//   [144..271]  fw1[8][16]
//   [272..279]  fb1[8]
//   [280..287]  fw2[8]
//   [288]       fb2
//   [292..295]  sc[B]        (xnorm scale per batch)
//   [296..299]  ofs[B]       (xnorm offset per batch)
//   [320...]    pair planes: h4v plane[4][B*HW]  (10.5 MB)
#define WS_PAIR_OFF 320

// XCD band swizzle: each XCD owns a contiguous pixel band so its plane
// slice stays L2-resident across all 9 neighbor passes.
__device__ __forceinline__ int swz_band(int bid, int per_xcd) {
    return (bid & 7) * per_xcd + (bid >> 3);
}

// ---------------- Kernel 0: fold BN into weights, precompute xnorm affine ----------------
__global__ void k_setup(
    const float* __restrict__ dmin, const float* __restrict__ dmax,
    const float* __restrict__ w0, const float* __restrict__ g0, const float* __restrict__ b0,
    const float* __restrict__ m0, const float* __restrict__ v0,
    const float* __restrict__ w1, const float* __restrict__ g1, const float* __restrict__ b1,
    const float* __restrict__ m1, const float* __restrict__ v1,
    const float* __restrict__ w2, const float* __restrict__ b2,
    float* __restrict__ ws)
{
    int t = threadIdx.x;
    if (t < 16) {
        float inv   = g0[t] * rsqrtf(v0[t] + BN_EPS);
        float shift = b0[t] - m0[t] * inv;
        for (int g = 0; g < G_; ++g) ws[t * G_ + g] = w0[t * G_ + g] * inv;
        ws[128 + t] = shift;
    }
    if (t < 8) {
        float inv   = g1[t] * rsqrtf(v1[t] + BN_EPS);
        float shift = b1[t] - m1[t] * inv;
        for (int i = 0; i < 16; ++i) ws[144 + t * 16 + i] = w1[t * 16 + i] * inv;
        ws[272 + t] = shift;
        ws[280 + t] = w2[t];
    }
    if (t == 0) ws[288] = b2[0];
    if (t < B_) {
        float imin = 1.0f / dmin[t];
        float imax = 1.0f / dmax[t];
        float sc   = 1.0f / (imin - imax);
        ws[292 + t] = sc;
        ws[296 + t] = -imax * sc;
    }
}

// ---------------- MLP for one pixel-depth: G costs -> s ----------------
__device__ __forceinline__ float mlp_eval(const float c[G_], const float* __restrict__ ws) {
    float h0[16];
#pragma unroll
    for (int o = 0; o < 16; ++o) {
        float acc = ws[128 + o];
#pragma unroll
        for (int g = 0; g < G_; ++g) acc = fmaf(c[g], ws[o * G_ + g], acc);
        h0[o] = fmaxf(acc, 0.0f);
    }
    float h1[8];
#pragma unroll
    for (int o = 0; o < 8; ++o) {
        float acc = ws[272 + o];
#pragma unroll
        for (int i = 0; i < 16; ++i) acc = fmaf(h0[i], ws[144 + o * 16 + i], acc);
        h1[o] = fmaxf(acc, 0.0f);
    }
    float s = ws[288];
#pragma unroll
    for (int i = 0; i < 8; ++i) s = fmaf(h1[i], ws[280 + i], s);
    return s;
}

// ---------------- Kernel 1: one thread per (pixel, depth-pair) ----------------
__global__ __launch_bounds__(256) void k_s_xnorm(
    const float* __restrict__ cost,      // [B,G,D,H,W]
    const float* __restrict__ dsamp,     // [B,D,H,W]
    const float* __restrict__ ws,
    h4v* __restrict__ plane)             // [4][B*HW]
{
    int tid = swz_band(blockIdx.x, 640) * 256 + threadIdx.x;  // over B*HW*4
    int j   = tid & 3;
    int idx = tid >> 2;          // b*HW + pix
    int b   = idx / HW;
    int pix = idx % HW;
    int d0  = j * 2;

    float sc  = ws[292 + b];
    float ofs = ws[296 + b];

    const float* cb = cost  + (size_t)b * G_ * DHW + (size_t)d0 * HW + pix;
    const float* db = dsamp + (size_t)b * DHW + (size_t)d0 * HW + pix;

    float c0[G_], c1[G_];
#pragma unroll
    for (int g = 0; g < G_; ++g) {
        c0[g] = cb[(size_t)g * DHW];
        c1[g] = cb[(size_t)g * DHW + HW];
    }

    float s0 = mlp_eval(c0, ws);
    float s1 = mlp_eval(c1, ws);

    float xn0 = fmaf(__builtin_amdgcn_rcpf(db[0]),  sc, ofs);
    float xn1 = fmaf(__builtin_amdgcn_rcpf(db[HW]), sc, ofs);

    h4v res;
    res[0] = (_Float16)xn0;
    res[1] = (_Float16)s0;
    res[2] = (_Float16)xn1;
    res[3] = (_Float16)s1;

    plane[(size_t)j * BHW + idx] = res;
}

// ---- one bilinear tap-set -> update two depth accumulators ----
__device__ __forceinline__ void tap_accum(
    h4v t, h4v u, h4v v, h4v z,
    float w00, float w01, float w10, float w11, float fw,
    float xnc0, float xnc1, float& acc0, float& acc1)
{
    float xs0 = w00 * (float)t[0] + w01 * (float)u[0] + w10 * (float)v[0] + w11 * (float)z[0];
    float ss0 = w00 * (float)t[1] + w01 * (float)u[1] + w10 * (float)v[1] + w11 * (float)z[1];
    float xs1 = w00 * (float)t[2] + w01 * (float)u[2] + w10 * (float)v[2] + w11 * (float)z[2];
    float ss1 = w00 * (float)t[3] + w01 * (float)u[3] + w10 * (float)v[3] + w11 * (float)z[3];
    float df0 = fminf(fabsf(xs0 - xnc0) * 40.0f, 4.0f);
    float df1 = fminf(fabsf(xs1 - xnc1) * 40.0f, 4.0f);
    float dw0 = __builtin_amdgcn_rcpf(1.0f + __expf(2.0f * df0 - 4.0f));
    float dw1 = __builtin_amdgcn_rcpf(1.0f + __expf(2.0f * df1 - 4.0f));
    acc0 = fmaf(ss0 * fw, dw0, acc0);
    acc1 = fmaf(ss1 * fw, dw1, acc1);
}

__device__ __forceinline__ h4v lo4(h8v r) { h4v o; o[0]=r[0]; o[1]=r[1]; o[2]=r[2]; o[3]=r[3]; return o; }
__device__ __forceinline__ h4v hi4(h8v r) { h4v o; o[0]=r[4]; o[1]=r[5]; o[2]=r[6]; o[3]=r[7]; return o; }

// ---------------- Kernel 2: neighbor gather + sigmoid kernel + aggregate ----------------
// ONE THREAD PER 2 ADJACENT PIXELS (px0 even, px1 = px0+1, same row).
// The sampling grid is base+jitter with near-constant per-(b,n) offset, so
// almost always x0(px1)==x0(px0)+1 and the two 2x2 tap footprints overlap 50%.
// Wave-uniform fast path shares tap loads: per neighbor per plane, one h8v +
// one h4v per row (24B for both pixels) vs 2 overlapping h8v. Slow path
// (border/irregular waves, ~8%) computes each pixel independently -> generic
// correctness. Fully unrolled over 9 neighbors for MLP.
__global__ __launch_bounds__(256) void k_aggregate(
    const float* __restrict__ grid,      // [B, N*H, W, 2]
    const float* __restrict__ fweight,   // [B, N, H, W]
    const h4v* __restrict__ plane,       // [4][B*HW]
    float* __restrict__ out)             // [B,D,H,W]
{
    int t    = swz_band(blockIdx.x, 80) * 256 + threadIdx.x;  // over B*HW/2
    int px0g = t * 2;                 // global even pixel (b*HW + pix0)
    int b    = px0g / HW;
    int pix0 = px0g % HW;
    int h    = pix0 / W_;
    int wq   = pix0 % W_;             // even

    const float* gbase = grid + (((size_t)b * (N_ * H_) + h) * W_ + wq) * 2;
    const float* fbase = fweight + ((size_t)b * N_ + 0) * HW + (size_t)h * W_ + wq;

    // ---- center xnorm for both pixels (contiguous h8v per plane) ----
    float xncA[D_], xncB[D_];
#pragma unroll
    for (int j = 0; j < 4; ++j) {
        h8v c = *(const h8v*)(plane + (size_t)j * BHW + px0g);
        xncA[2 * j]     = (float)c[0];
        xncA[2 * j + 1] = (float)c[2];
        xncB[2 * j]     = (float)c[4];
        xncB[2 * j + 1] = (float)c[6];
    }

    float accA[D_], accB[D_];
#pragma unroll
    for (int d = 0; d < D_; ++d) { accA[d] = 0.0f; accB[d] = 0.0f; }

    const int bbase = b * HW;

#pragma unroll
    for (int n = 0; n < N_; ++n) {
        float4 gq  = *(const float4*)(gbase + (size_t)n * (H_ * W_) * 2);  // grid px0,px1
        float2 fwp = *(const float2*)(fbase + (size_t)n * HW);

        // ---- px0 coords ----
        float gxa = fminf(fmaxf((gq.x + 1.0f) * 0.5f * W_ - 0.5f, 0.0f), (float)(W_ - 1));
        float gya = fminf(fmaxf((gq.y + 1.0f) * 0.5f * H_ - 0.5f, 0.0f), (float)(H_ - 1));
        float xa0f = floorf(gxa), ya0f = floorf(gya);
        float wxa = gxa - xa0f, wya = gya - ya0f;
        int xa0 = (int)xa0f, ya0 = (int)ya0f;
        int ya1 = min(ya0 + 1, H_ - 1);
        float wa00 = (1.0f - wxa) * (1.0f - wya);
        float wa01 = wxa * (1.0f - wya);
        float wa10 = (1.0f - wxa) * wya;
        float wa11 = wxa * wya;

        // ---- px1 coords ----
        float gxb = fminf(fmaxf((gq.z + 1.0f) * 0.5f * W_ - 0.5f, 0.0f), (float)(W_ - 1));
        float gyb = fminf(fmaxf((gq.w + 1.0f) * 0.5f * H_ - 0.5f, 0.0f), (float)(H_ - 1));
        float xb0f = floorf(gxb), yb0f = floorf(gyb);
        float wxb = gxb - xb0f, wyb = gyb - yb0f;
        int xb0 = (int)xb0f, yb0 = (int)yb0f;
        int yb1 = min(yb0 + 1, H_ - 1);
        float wb00 = (1.0f - wxb) * (1.0f - wyb);
        float wb01 = wxb * (1.0f - wyb);
        float wb10 = (1.0f - wxb) * wyb;
        float wb11 = wxb * wyb;

        bool fast = __all(yb0 == ya0 && xb0 == xa0 + 1 && xb0 < W_ - 1);

        int oA = bbase + ya0 * W_ + xa0;
        int oB = bbase + ya1 * W_ + xa0;

        if (fast) {
            // shared footprint: quads [xa0, xa0+1, xa0+2] on rows ya0, ya1
#pragma unroll
            for (int j = 0; j < 4; ++j) {
                const h4v* pj = plane + (size_t)j * BHW;
                h8v ra8 = *(const h8v*)(pj + oA);
                h4v ra4 = pj[oA + 2];
                h8v rb8 = *(const h8v*)(pj + oB);
                h4v rb4 = pj[oB + 2];
                tap_accum(lo4(ra8), hi4(ra8), lo4(rb8), hi4(rb8),
                          wa00, wa01, wa10, wa11, fwp.x,
                          xncA[2 * j], xncA[2 * j + 1], accA[2 * j], accA[2 * j + 1]);
                tap_accum(hi4(ra8), ra4, hi4(rb8), rb4,
                          wb00, wb01, wb10, wb11, fwp.y,
                          xncB[2 * j], xncB[2 * j + 1], accB[2 * j], accB[2 * j + 1]);
            }
        } else {
            int oAb = bbase + yb0 * W_ + xb0;
            int oBb = bbase + yb1 * W_ + xb0;
#pragma unroll
            for (int j = 0; j < 4; ++j) {
                const h4v* pj = plane + (size_t)j * BHW;
                h8v raA = *(const h8v*)(pj + oA);
                h8v rbA = *(const h8v*)(pj + oB);
                h8v raB = *(const h8v*)(pj + oAb);
                h8v rbB = *(const h8v*)(pj + oBb);
                // x0==W-1 only when wx==0 (clamped), so the OOB-row upper quad
                // always carries zero weight.
                tap_accum(lo4(raA), hi4(raA), lo4(rbA), hi4(rbA),
                          wa00, wa01, wa10, wa11, fwp.x,
                          xncA[2 * j], xncA[2 * j + 1], accA[2 * j], accA[2 * j + 1]);
                tap_accum(lo4(raB), hi4(raB), lo4(rbB), hi4(rbB),
                          wb00, wb01, wb10, wb11, fwp.y,
                          xncB[2 * j], xncB[2 * j + 1], accB[2 * j], accB[2 * j + 1]);
            }
        }
    }

    // ---- write both pixels: one float2 per depth plane ----
#pragma unroll
    for (int d = 0; d < D_; ++d) {
        float2 o2; o2.x = accA[d]; o2.y = accB[d];
        *(float2*)(out + ((size_t)b * D_ + d) * HW + pix0) = o2;
    }
}

extern "C" void kernel_launch(void* const* d_in, const int* in_sizes, int n_in,
                              void* d_out, int out_size, void* d_ws, size_t ws_size,
                              hipStream_t stream) {
    const float* cost    = (const float*)d_in[0];
    const float* dsamp   = (const float*)d_in[1];
    const float* dmin    = (const float*)d_in[2];
    const float* dmax    = (const float*)d_in[3];
    const float* grid    = (const float*)d_in[4];
    const float* fweight = (const float*)d_in[5];
    const float* w0 = (const float*)d_in[6];
    const float* g0 = (const float*)d_in[7];
    const float* b0 = (const float*)d_in[8];
    const float* m0 = (const float*)d_in[9];
    const float* v0 = (const float*)d_in[10];
    const float* w1 = (const float*)d_in[11];
    const float* g1 = (const float*)d_in[12];
    const float* b1 = (const float*)d_in[13];
    const float* m1 = (const float*)d_in[14];
    const float* v1 = (const float*)d_in[15];
    const float* w2 = (const float*)d_in[16];
    const float* b2 = (const float*)d_in[17];
    float* out = (float*)d_out;

    float* ws    = (float*)d_ws;
    h4v*   plane = (h4v*)(ws + WS_PAIR_OFF);

    k_setup<<<1, 64, 0, stream>>>(dmin, dmax,
                                  w0, g0, b0, m0, v0,
                                  w1, g1, b1, m1, v1,
                                  w2, b2, ws);

    // k1: 5120 blocks over (pixel, depth-pair); k2: 640 blocks over pixel
    // pairs. Both map pixel p -> XCD p/40960 (producer/consumer L2 affinity).
    k_s_xnorm<<<5120, 256, 0, stream>>>(cost, dsamp, ws, plane);
    k_aggregate<<<640, 256, 0, stream>>>(grid, fweight, plane, out);
}

// Round 12
// 54.326 us; speedup vs baseline: 1.1814x; 1.1814x over previous
//
#include <hip/hip_runtime.h>
#include <math.h>

// Problem dims (fixed by setup_inputs)
#define B_ 4
#define G_ 8
#define D_ 8
#define H_ 256
#define W_ 320
#define N_ 9
constexpr int HW  = H_ * W_;
constexpr int DHW = D_ * HW;
constexpr int BHW = B_ * HW;
constexpr float BN_EPS = 1e-5f;

// fp16 quad: {xn(2j), s(2j), xn(2j+1), s(2j+1)} for one pixel, one depth-pair.
typedef _Float16 h4v __attribute__((ext_vector_type(4)));
// two adjacent pixels' quads (16 B): [0..3] = pixel x0, [4..7] = pixel x0+1
typedef _Float16 h8v __attribute__((ext_vector_type(8)));

// d_ws float layout:
//   [0..127]    fw0[16][8]   (BN-folded layer0 weights)
//   [128..143]  fb0[16]      (BN-folded layer0 bias)
//   [144..271]  fw1[8][16]
//   [272..279]  fb1[8]
//   [280..287]  fw2[8]
//   [288]       fb2
//   [292..295]  sc[B]        (xnorm scale per batch)
//   [296..299]  ofs[B]       (xnorm offset per batch)
//   [320...]    pair planes: h4v plane[4][B*HW]  (10.5 MB)
#define WS_PAIR_OFF 320

// XCD band swizzle: each XCD owns a contiguous pixel band so its plane
// slice stays L2-resident across all 9 neighbor passes.
__device__ __forceinline__ int swz_band(int bid, int per_xcd) {
    return (bid & 7) * per_xcd + (bid >> 3);
}

// ---------------- Kernel 0: fold BN into weights, precompute xnorm affine ----------------
__global__ void k_setup(
    const float* __restrict__ dmin, const float* __restrict__ dmax,
    const float* __restrict__ w0, const float* __restrict__ g0, const float* __restrict__ b0,
    const float* __restrict__ m0, const float* __restrict__ v0,
    const float* __restrict__ w1, const float* __restrict__ g1, const float* __restrict__ b1,
    const float* __restrict__ m1, const float* __restrict__ v1,
    const float* __restrict__ w2, const float* __restrict__ b2,
    float* __restrict__ ws)
{
    int t = threadIdx.x;
    if (t < 16) {
        float inv   = g0[t] * rsqrtf(v0[t] + BN_EPS);
        float shift = b0[t] - m0[t] * inv;
        for (int g = 0; g < G_; ++g) ws[t * G_ + g] = w0[t * G_ + g] * inv;
        ws[128 + t] = shift;
    }
    if (t < 8) {
        float inv   = g1[t] * rsqrtf(v1[t] + BN_EPS);
        float shift = b1[t] - m1[t] * inv;
        for (int i = 0; i < 16; ++i) ws[144 + t * 16 + i] = w1[t * 16 + i] * inv;
        ws[272 + t] = shift;
        ws[280 + t] = w2[t];
    }
    if (t == 0) ws[288] = b2[0];
    if (t < B_) {
        float imin = 1.0f / dmin[t];
        float imax = 1.0f / dmax[t];
        float sc   = 1.0f / (imin - imax);
        ws[292 + t] = sc;
        ws[296 + t] = -imax * sc;
    }
}

// ---------------- MLP for one pixel-depth: G costs -> s ----------------
__device__ __forceinline__ float mlp_eval(const float c[G_], const float* __restrict__ ws) {
    float h0[16];
#pragma unroll
    for (int o = 0; o < 16; ++o) {
        float acc = ws[128 + o];
#pragma unroll
        for (int g = 0; g < G_; ++g) acc = fmaf(c[g], ws[o * G_ + g], acc);
        h0[o] = fmaxf(acc, 0.0f);
    }
    float h1[8];
#pragma unroll
    for (int o = 0; o < 8; ++o) {
        float acc = ws[272 + o];
#pragma unroll
        for (int i = 0; i < 16; ++i) acc = fmaf(h0[i], ws[144 + o * 16 + i], acc);
        h1[o] = fmaxf(acc, 0.0f);
    }
    float s = ws[288];
#pragma unroll
    for (int i = 0; i < 8; ++i) s = fmaf(h1[i], ws[280 + i], s);
    return s;
}

// ---------------- Kernel 1: one thread per (pixel, depth-pair) ----------------
__global__ __launch_bounds__(256) void k_s_xnorm(
    const float* __restrict__ cost,      // [B,G,D,H,W]
    const float* __restrict__ dsamp,     // [B,D,H,W]
    const float* __restrict__ ws,
    h4v* __restrict__ plane)             // [4][B*HW]
{
    int tid = swz_band(blockIdx.x, 640) * 256 + threadIdx.x;  // over B*HW*4
    int j   = tid & 3;
    int idx = tid >> 2;          // b*HW + pix
    int b   = idx / HW;
    int pix = idx % HW;
    int d0  = j * 2;

    float sc  = ws[292 + b];
    float ofs = ws[296 + b];

    const float* cb = cost  + (size_t)b * G_ * DHW + (size_t)d0 * HW + pix;
    const float* db = dsamp + (size_t)b * DHW + (size_t)d0 * HW + pix;

    float c0[G_], c1[G_];
#pragma unroll
    for (int g = 0; g < G_; ++g) {
        c0[g] = cb[(size_t)g * DHW];
        c1[g] = cb[(size_t)g * DHW + HW];
    }

    float s0 = mlp_eval(c0, ws);
    float s1 = mlp_eval(c1, ws);

    float xn0 = fmaf(__builtin_amdgcn_rcpf(db[0]),  sc, ofs);
    float xn1 = fmaf(__builtin_amdgcn_rcpf(db[HW]), sc, ofs);

    h4v res;
    res[0] = (_Float16)xn0;
    res[1] = (_Float16)s0;
    res[2] = (_Float16)xn1;
    res[3] = (_Float16)s1;

    plane[(size_t)j * BHW + idx] = res;
}

__device__ __forceinline__ h4v lo4(h8v r) { h4v o; o[0]=r[0]; o[1]=r[1]; o[2]=r[2]; o[3]=r[3]; return o; }
__device__ __forceinline__ h4v hi4(h8v r) { h4v o; o[0]=r[4]; o[1]=r[5]; o[2]=r[6]; o[3]=r[7]; return o; }

// ---------------- Kernel 2: neighbor gather + sigmoid kernel + aggregate ----------------
// 1 thread per pixel, all 8 depths, FULLY UNROLLED over 9 neighbors (round-10
// structure: ~90 independent loads in flight). NEW: bilinear lerp done in
// PACKED fp16 (v_pk_fma_f16 on the h4v quads) — 12 packed ops + 4 cvts per
// plane instead of 16 cvts + 20 fp32 ops. diff/sigmoid stay fp32.
// Per neighbor per plane: ONE 16B load covers both x-taps of a row.
// Border: x0==W-1 implies wx==0 exactly -> OOB second quad gets zero weight.
__global__ __launch_bounds__(256) void k_aggregate(
    const float* __restrict__ grid,      // [B, N*H, W, 2]
    const float* __restrict__ fweight,   // [B, N, H, W]
    const h4v* __restrict__ plane,       // [4][B*HW]
    float* __restrict__ out)             // [B,D,H,W]
{
    int idx = swz_band(blockIdx.x, 160) * 256 + threadIdx.x;  // b*HW + pix
    int b   = idx / HW;
    int pix = idx % HW;
    int h   = pix / W_;
    int wq  = pix % W_;

    const float2* gpx = (const float2*)grid + (size_t)b * (N_ * H_) * W_ + (size_t)h * W_ + wq;
    const float*  fpx = fweight + (size_t)b * N_ * HW + (size_t)h * W_ + wq;

    // ---- center xnorm per depth ----
    float xnc[D_];
#pragma unroll
    for (int j = 0; j < 4; ++j) {
        h4v v = plane[(size_t)j * BHW + idx];
        xnc[2 * j]     = (float)v[0];
        xnc[2 * j + 1] = (float)v[2];
    }

    float acc[D_];
#pragma unroll
    for (int d = 0; d < D_; ++d) acc[d] = 0.0f;

    const int bbase = b * HW;

#pragma unroll
    for (int n = 0; n < N_; ++n) {
        float2 g  = gpx[(size_t)n * (H_ * W_)];
        float  fw = fpx[(size_t)n * HW];

        // align_corners=False, border padding
        float gxp = fminf(fmaxf((g.x + 1.0f) * 0.5f * W_ - 0.5f, 0.0f), (float)(W_ - 1));
        float gyp = fminf(fmaxf((g.y + 1.0f) * 0.5f * H_ - 0.5f, 0.0f), (float)(H_ - 1));
        float x0f = floorf(gxp);
        float y0f = floorf(gyp);
        float wx = gxp - x0f;          // == 0 exactly when x0 == W-1 (clamped)
        float wy = gyp - y0f;
        int x0 = (int)x0f;
        int y0 = (int)y0f;
        int y1 = min(y0 + 1, H_ - 1);

        // broadcast lerp weights to packed fp16
        _Float16 wxh = (_Float16)wx;
        _Float16 wyh = (_Float16)wy;
        h4v wxv = {wxh, wxh, wxh, wxh};
        h4v wyv = {wyh, wyh, wyh, wyh};

        int oA = bbase + y0 * W_ + x0;  // row y0: pixels x0 & x0+1 via one 16B load
        int oB = bbase + y1 * W_ + x0;  // row y1

#pragma unroll
        for (int j = 0; j < 4; ++j) {
            const h4v* pj = plane + (size_t)j * BHW;
            h8v rA = *(const h8v*)(pj + oA);
            h8v rB = *(const h8v*)(pj + oB);

            h4v tA = lo4(rA), uA = hi4(rA);
            h4v tB = lo4(rB), uB = hi4(rB);

            // packed fp16 bilinear: x-lerp both rows, then y-lerp
            h4v ax = tA + wxv * (uA - tA);
            h4v bx = tB + wxv * (uB - tB);
            h4v cy = ax + wyv * (bx - ax);   // {xs0, ss0, xs1, ss1}

            float xs0 = (float)cy[0];
            float ss0 = (float)cy[1];
            float xs1 = (float)cy[2];
            float ss1 = (float)cy[3];

            float df0 = fminf(fabsf(xs0 - xnc[2 * j]) * 40.0f, 4.0f);
            float df1 = fminf(fabsf(xs1 - xnc[2 * j + 1]) * 40.0f, 4.0f);
            float dw0 = __builtin_amdgcn_rcpf(1.0f + __expf(2.0f * df0 - 4.0f));
            float dw1 = __builtin_amdgcn_rcpf(1.0f + __expf(2.0f * df1 - 4.0f));
            acc[2 * j]     = fmaf(ss0 * fw, dw0, acc[2 * j]);
            acc[2 * j + 1] = fmaf(ss1 * fw, dw1, acc[2 * j + 1]);
        }
    }

#pragma unroll
    for (int d = 0; d < D_; ++d) out[(b * D_ + d) * HW + pix] = acc[d];
}

extern "C" void kernel_launch(void* const* d_in, const int* in_sizes, int n_in,
                              void* d_out, int out_size, void* d_ws, size_t ws_size,
                              hipStream_t stream) {
    const float* cost    = (const float*)d_in[0];
    const float* dsamp   = (const float*)d_in[1];
    const float* dmin    = (const float*)d_in[2];
    const float* dmax    = (const float*)d_in[3];
    const float* grid    = (const float*)d_in[4];
    const float* fweight = (const float*)d_in[5];
    const float* w0 = (const float*)d_in[6];
    const float* g0 = (const float*)d_in[7];
    const float* b0 = (const float*)d_in[8];
    const float* m0 = (const float*)d_in[9];
    const float* v0 = (const float*)d_in[10];
    const float* w1 = (const float*)d_in[11];
    const float* g1 = (const float*)d_in[12];
    const float* b1 = (const float*)d_in[13];
    const float* m1 = (const float*)d_in[14];
    const float* v1 = (const float*)d_in[15];
    const float* w2 = (const float*)d_in[16];
    const float* b2 = (const float*)d_in[17];
    float* out = (float*)d_out;

    float* ws    = (float*)d_ws;
    h4v*   plane = (h4v*)(ws + WS_PAIR_OFF);

    k_setup<<<1, 64, 0, stream>>>(dmin, dmax,
                                  w0, g0, b0, m0, v0,
                                  w1, g1, b1, m1, v1,
                                  w2, b2, ws);

    // k1: 5120 blocks over (pixel, depth-pair); k2: 1280 blocks over pixels.
    // Both map pixel p -> XCD p/40960 (producer/consumer L2 affinity).
    k_s_xnorm<<<5120, 256, 0, stream>>>(cost, dsamp, ws, plane);
    k_aggregate<<<1280, 256, 0, stream>>>(grid, fweight, plane, out);
}

// Round 13
// 52.393 us; speedup vs baseline: 1.2250x; 1.0369x over previous
//
#include <hip/hip_runtime.h>
#include <math.h>

// Problem dims (fixed by setup_inputs)
#define B_ 4
#define G_ 8
#define D_ 8
#define H_ 256
#define W_ 320
#define N_ 9
constexpr int HW  = H_ * W_;
constexpr int DHW = D_ * HW;
constexpr int BHW = B_ * HW;
constexpr float BN_EPS = 1e-5f;

// fp16 quad per (pixel, depth-pair j): {xn(2j), xn(2j+1), s(2j), s(2j+1)}
// -> low 32 bits = xn pair, high 32 bits = s pair (packed-friendly).
typedef _Float16 h2v __attribute__((ext_vector_type(2)));
typedef _Float16 h4v __attribute__((ext_vector_type(4)));
typedef _Float16 h8v __attribute__((ext_vector_type(8)));

// d_ws float layout:
//   [0..127]    fw0[16][8]   (BN-folded layer0 weights)
//   [128..143]  fb0[16]      (BN-folded layer0 bias)
//   [144..271]  fw1[8][16]
//   [272..279]  fb1[8]
//   [280..287]  fw2[8]
//   [288]       fb2
//   [292..295]  sc[B]        (xnorm scale per batch)
//   [296..299]  ofs[B]       (xnorm offset per batch)
//   [320...]    pair planes: h4v plane[4][B*HW]  (10.5 MB)
#define WS_PAIR_OFF 320

// XCD band swizzle: each XCD owns a contiguous pixel band so its plane
// slice stays L2-resident across all 9 neighbor passes.
__device__ __forceinline__ int swz_band(int bid, int per_xcd) {
    return (bid & 7) * per_xcd + (bid >> 3);
}

// ---------------- Kernel 0: fold BN into weights, precompute xnorm affine ----------------
__global__ void k_setup(
    const float* __restrict__ dmin, const float* __restrict__ dmax,
    const float* __restrict__ w0, const float* __restrict__ g0, const float* __restrict__ b0,
    const float* __restrict__ m0, const float* __restrict__ v0,
    const float* __restrict__ w1, const float* __restrict__ g1, const float* __restrict__ b1,
    const float* __restrict__ m1, const float* __restrict__ v1,
    const float* __restrict__ w2, const float* __restrict__ b2,
    float* __restrict__ ws)
{
    int t = threadIdx.x;
    if (t < 16) {
        float inv   = g0[t] * rsqrtf(v0[t] + BN_EPS);
        float shift = b0[t] - m0[t] * inv;
        for (int g = 0; g < G_; ++g) ws[t * G_ + g] = w0[t * G_ + g] * inv;
        ws[128 + t] = shift;
    }
    if (t < 8) {
        float inv   = g1[t] * rsqrtf(v1[t] + BN_EPS);
        float shift = b1[t] - m1[t] * inv;
        for (int i = 0; i < 16; ++i) ws[144 + t * 16 + i] = w1[t * 16 + i] * inv;
        ws[272 + t] = shift;
        ws[280 + t] = w2[t];
    }
    if (t == 0) ws[288] = b2[0];
    if (t < B_) {
        float imin = 1.0f / dmin[t];
        float imax = 1.0f / dmax[t];
        float sc   = 1.0f / (imin - imax);
        ws[292 + t] = sc;
        ws[296 + t] = -imax * sc;
    }
}

// ---------------- MLP for one pixel-depth: G costs -> s ----------------
__device__ __forceinline__ float mlp_eval(const float c[G_], const float* __restrict__ ws) {
    float h0[16];
#pragma unroll
    for (int o = 0; o < 16; ++o) {
        float acc = ws[128 + o];
#pragma unroll
        for (int g = 0; g < G_; ++g) acc = fmaf(c[g], ws[o * G_ + g], acc);
        h0[o] = fmaxf(acc, 0.0f);
    }
    float h1[8];
#pragma unroll
    for (int o = 0; o < 8; ++o) {
        float acc = ws[272 + o];
#pragma unroll
        for (int i = 0; i < 16; ++i) acc = fmaf(h0[i], ws[144 + o * 16 + i], acc);
        h1[o] = fmaxf(acc, 0.0f);
    }
    float s = ws[288];
#pragma unroll
    for (int i = 0; i < 8; ++i) s = fmaf(h1[i], ws[280 + i], s);
    return s;
}

// ---------------- Kernel 1: one thread per (pixel, depth-pair) ----------------
__global__ __launch_bounds__(256) void k_s_xnorm(
    const float* __restrict__ cost,      // [B,G,D,H,W]
    const float* __restrict__ dsamp,     // [B,D,H,W]
    const float* __restrict__ ws,
    h4v* __restrict__ plane)             // [4][B*HW]
{
    int tid = swz_band(blockIdx.x, 640) * 256 + threadIdx.x;  // over B*HW*4
    int j   = tid & 3;
    int idx = tid >> 2;          // b*HW + pix
    int b   = idx / HW;
    int pix = idx % HW;
    int d0  = j * 2;

    float sc  = ws[292 + b];
    float ofs = ws[296 + b];

    const float* cb = cost  + (size_t)b * G_ * DHW + (size_t)d0 * HW + pix;
    const float* db = dsamp + (size_t)b * DHW + (size_t)d0 * HW + pix;

    float c0[G_], c1[G_];
#pragma unroll
    for (int g = 0; g < G_; ++g) {
        c0[g] = cb[(size_t)g * DHW];
        c1[g] = cb[(size_t)g * DHW + HW];
    }

    float s0 = mlp_eval(c0, ws);
    float s1 = mlp_eval(c1, ws);

    float xn0 = fmaf(__builtin_amdgcn_rcpf(db[0]),  sc, ofs);
    float xn1 = fmaf(__builtin_amdgcn_rcpf(db[HW]), sc, ofs);

    // layout: {xn0, xn1, s0, s1} -> packed xn pair low, s pair high
    h4v res;
    res[0] = (_Float16)xn0;
    res[1] = (_Float16)xn1;
    res[2] = (_Float16)s0;
    res[3] = (_Float16)s1;

    plane[(size_t)j * BHW + idx] = res;
}

__device__ __forceinline__ h4v lo4(h8v r) { h4v o; o[0]=r[0]; o[1]=r[1]; o[2]=r[2]; o[3]=r[3]; return o; }
__device__ __forceinline__ h4v hi4(h8v r) { h4v o; o[0]=r[4]; o[1]=r[5]; o[2]=r[6]; o[3]=r[7]; return o; }

// ---------------- Kernel 2: neighbor gather + sigmoid kernel + aggregate ----------------
// 1 thread per pixel, all 8 depths, FULLY UNROLLED over 9 neighbors.
// Bilinear lerp in packed fp16 (round 12). NEW: sigmoid replaced by a
// packed-fp16 odd polynomial: dw = 0.5 + y*P(y^2), y = 2 - min(40|dx|,4),
// P cubic fitted at Chebyshev nodes (|err| <= ~2e-3) -> no v_exp/v_rcp
// transcendentals (8 slot-cyc each), tail ~24 slot-cyc vs 68.
// Per neighbor per plane: ONE 16B load covers both x-taps of a row.
// Border: x0==W-1 implies wx==0 exactly -> OOB second quad gets zero weight.
__global__ __launch_bounds__(256) void k_aggregate(
    const float* __restrict__ grid,      // [B, N*H, W, 2]
    const float* __restrict__ fweight,   // [B, N, H, W]
    const h4v* __restrict__ plane,       // [4][B*HW]
    float* __restrict__ out)             // [B,D,H,W]
{
    int idx = swz_band(blockIdx.x, 160) * 256 + threadIdx.x;  // b*HW + pix
    int b   = idx / HW;
    int pix = idx % HW;
    int h   = pix / W_;
    int wq  = pix % W_;

    const float2* gpx = (const float2*)grid + (size_t)b * (N_ * H_) * W_ + (size_t)h * W_ + wq;
    const float*  fpx = fweight + (size_t)b * N_ * HW + (size_t)h * W_ + wq;

    // ---- center xnorm pair per plane ----
    h2v xnc2[4];
#pragma unroll
    for (int j = 0; j < 4; ++j) {
        h4v v = plane[(size_t)j * BHW + idx];
        h2v p; p[0] = v[0]; p[1] = v[1];
        xnc2[j] = p;
    }

    float acc[D_];
#pragma unroll
    for (int d = 0; d < D_; ++d) acc[d] = 0.0f;

    const int bbase = b * HW;

    const _Float16 kC0 = (_Float16)0.4974878f;
    const _Float16 kC1 = (_Float16)(-0.1454196f);
    const _Float16 kC2 = (_Float16)0.0327724f;
    const _Float16 kC3 = (_Float16)(-0.0031269f);
    const h2v c0v = {kC0, kC0};
    const h2v c1v = {kC1, kC1};
    const h2v c2v = {kC2, kC2};
    const h2v c3v = {kC3, kC3};
    const h2v n40 = {(_Float16)(-40.0f), (_Float16)(-40.0f)};
    const h2v two = {(_Float16)2.0f, (_Float16)2.0f};
    const h2v ntwo = {(_Float16)(-2.0f), (_Float16)(-2.0f)};
    const h2v halfv = {(_Float16)0.5f, (_Float16)0.5f};

#pragma unroll
    for (int n = 0; n < N_; ++n) {
        float2 g  = gpx[(size_t)n * (H_ * W_)];
        float  fw = fpx[(size_t)n * HW];

        // align_corners=False, border padding
        float gxp = fminf(fmaxf((g.x + 1.0f) * 0.5f * W_ - 0.5f, 0.0f), (float)(W_ - 1));
        float gyp = fminf(fmaxf((g.y + 1.0f) * 0.5f * H_ - 0.5f, 0.0f), (float)(H_ - 1));
        float x0f = floorf(gxp);
        float y0f = floorf(gyp);
        float wx = gxp - x0f;          // == 0 exactly when x0 == W-1 (clamped)
        float wy = gyp - y0f;
        int x0 = (int)x0f;
        int y0 = (int)y0f;
        int y1 = min(y0 + 1, H_ - 1);

        _Float16 wxh = (_Float16)wx;
        _Float16 wyh = (_Float16)wy;
        h4v wxv = {wxh, wxh, wxh, wxh};
        h4v wyv = {wyh, wyh, wyh, wyh};

        int oA = bbase + y0 * W_ + x0;  // row y0: pixels x0 & x0+1 via one 16B load
        int oB = bbase + y1 * W_ + x0;  // row y1

#pragma unroll
        for (int j = 0; j < 4; ++j) {
            const h4v* pj = plane + (size_t)j * BHW;
            h8v rA = *(const h8v*)(pj + oA);
            h8v rB = *(const h8v*)(pj + oB);

            h4v tA = lo4(rA), uA = hi4(rA);
            h4v tB = lo4(rB), uB = hi4(rB);

            // packed fp16 bilinear: x-lerp both rows, then y-lerp
            h4v ax = tA + wxv * (uA - tA);
            h4v bx = tB + wxv * (uB - tB);
            h4v cy = ax + wyv * (bx - ax);   // {xs0, xs1, ss0, ss1}

            h2v xs2; xs2[0] = cy[0]; xs2[1] = cy[1];
            h2v ss2; ss2[0] = cy[2]; ss2[1] = cy[3];

            // dw = 0.5 + y*P(y^2), y = max(2 - 40|xs-xnc|, -2)
            h2v del  = xs2 - xnc2[j];
            h2v absd = __builtin_elementwise_max(del, -del);
            h2v y2   = __builtin_elementwise_max(two + n40 * absd, ntwo);
            h2v u2   = y2 * y2;
            h2v P    = c2v + u2 * c3v;
            P        = c1v + u2 * P;
            P        = c0v + u2 * P;
            h2v dw2  = halfv + y2 * P;
            h2v pr   = dw2 * ss2;

            acc[2 * j]     = fmaf((float)pr[0], fw, acc[2 * j]);
            acc[2 * j + 1] = fmaf((float)pr[1], fw, acc[2 * j + 1]);
        }
    }

#pragma unroll
    for (int d = 0; d < D_; ++d) out[(b * D_ + d) * HW + pix] = acc[d];
}

extern "C" void kernel_launch(void* const* d_in, const int* in_sizes, int n_in,
                              void* d_out, int out_size, void* d_ws, size_t ws_size,
                              hipStream_t stream) {
    const float* cost    = (const float*)d_in[0];
    const float* dsamp   = (const float*)d_in[1];
    const float* dmin    = (const float*)d_in[2];
    const float* dmax    = (const float*)d_in[3];
    const float* grid    = (const float*)d_in[4];
    const float* fweight = (const float*)d_in[5];
    const float* w0 = (const float*)d_in[6];
    const float* g0 = (const float*)d_in[7];
    const float* b0 = (const float*)d_in[8];
    const float* m0 = (const float*)d_in[9];
    const float* v0 = (const float*)d_in[10];
    const float* w1 = (const float*)d_in[11];
    const float* g1 = (const float*)d_in[12];
    const float* b1 = (const float*)d_in[13];
    const float* m1 = (const float*)d_in[14];
    const float* v1 = (const float*)d_in[15];
    const float* w2 = (const float*)d_in[16];
    const float* b2 = (const float*)d_in[17];
    float* out = (float*)d_out;

    float* ws    = (float*)d_ws;
    h4v*   plane = (h4v*)(ws + WS_PAIR_OFF);

    k_setup<<<1, 64, 0, stream>>>(dmin, dmax,
                                  w0, g0, b0, m0, v0,
                                  w1, g1, b1, m1, v1,
                                  w2, b2, ws);

    // k1: 5120 blocks over (pixel, depth-pair); k2: 1280 blocks over pixels.
    // Both map pixel p -> XCD p/40960 (producer/consumer L2 affinity).
    k_s_xnorm<<<5120, 256, 0, stream>>>(cost, dsamp, ws, plane);
    k_aggregate<<<1280, 256, 0, stream>>>(grid, fweight, plane, out);
}